// Round 2
// baseline (402.043 us; speedup 1.0000x reference)
//
#include <hip/hip_runtime.h>
#include <hip/hip_bf16.h>
#include <math.h>

#define B_ 16
#define NT 64
#define LN 256
#define LV 4
#define D_ 256
#define VOCAB_ 32000
#define M_ 128
#define LS 4
#define ECAP 352  // per-(bn,range) entry capacity; mean 262, sigma ~14 -> 6.4 sigma

typedef unsigned short ushort_t;
typedef unsigned int uint_t;

__device__ __forceinline__ ushort_t f2bf(float f) {
  uint_t u = __float_as_uint(f);
  uint_t r = u + 0x7FFFu + ((u >> 16) & 1u);
  return (ushort_t)(r >> 16);
}
__device__ __forceinline__ float bflo(uint_t u) {
  return __uint_as_float(u << 16);
}
__device__ __forceinline__ float bfhi(uint_t u) {
  return __uint_as_float(u & 0xFFFF0000u);
}

// ---------------- K_prep: S gather | C0->bf16 | W_ih^T | W_hh^T | TQK | WvT
// | bucketize kb entries by (value-range, type) -------------------------------
#define NB_S (3 * B_ * M_)  // 6144
#define NB_CONV 2048
#define NB_TR 192   // 768x256 -> 24x8 tiles of 32x32 (per weight)
#define NB_TQK 256
#define NB_WVT 64   // 256x256 -> 8x8 tiles
#define NB_BKT (B_ * NT)  // 1024 bucketing blocks
__global__ __launch_bounds__(256) void k_prep(
    const int* __restrict__ story, const float* __restrict__ C,
    const float* __restrict__ W_ih, const float* __restrict__ W_hh,
    const float* __restrict__ Wq, const float* __restrict__ Wk,
    const float* __restrict__ Wv, const int* __restrict__ kb_values,
    const int* __restrict__ kb_types, float* __restrict__ S,
    ushort_t* __restrict__ C0h, float* __restrict__ W_ihT,
    float* __restrict__ W_hhT, float* __restrict__ TQK,
    float* __restrict__ WvT, int* __restrict__ entries,
    int* __restrict__ counts) {
  __shared__ __align__(16) char praw[6400];
  float* smem = (float*)praw;  // 32*33 floats fit (4224 B)
  int blk = blockIdx.x, tid = threadIdx.x;
  if (blk < NB_S) {
    int h = blk / (B_ * M_);
    int bm = blk % (B_ * M_);
    const int* st = story + (size_t)bm * LS;
    const float* Ch = C + (size_t)h * VOCAB_ * D_;
    float s = Ch[(size_t)st[0] * D_ + tid] + Ch[(size_t)st[1] * D_ + tid] +
              Ch[(size_t)st[2] * D_ + tid] + Ch[(size_t)st[3] * D_ + tid];
    S[(size_t)blk * D_ + tid] = s;
  } else if (blk < NB_S + NB_CONV) {
    int n4 = VOCAB_ * D_ / 4;
    for (int i = (blk - NB_S) * 256 + tid; i < n4; i += NB_CONV * 256) {
      float4 f = ((const float4*)C)[i];
      uint2 packed;
      packed.x = (uint_t)f2bf(f.x) | ((uint_t)f2bf(f.y) << 16);
      packed.y = (uint_t)f2bf(f.z) | ((uint_t)f2bf(f.w) << 16);
      ((uint2*)C0h)[i] = packed;
    }
  } else if (blk < NB_S + NB_CONV + 2 * NB_TR) {
    int t = blk - (NB_S + NB_CONV);
    const float* W = W_ih;
    float* WT = W_ihT;
    if (t >= NB_TR) { t -= NB_TR; W = W_hh; WT = W_hhT; }
    const int R = 768;
    int tr = t % (R / 32), tc = t / (R / 32);
    int tx = tid & 31, ty = tid >> 5;
#pragma unroll
    for (int k = 0; k < 4; ++k)
      smem[(ty + 8 * k) * 33 + tx] =
          W[(size_t)(tr * 32 + ty + 8 * k) * D_ + tc * 32 + tx];
    __syncthreads();
#pragma unroll
    for (int k = 0; k < 4; ++k)
      WT[(size_t)(tc * 32 + ty + 8 * k) * R + tr * 32 + tx] =
          smem[tx * 33 + ty + 8 * k];
  } else if (blk < NB_S + NB_CONV + 2 * NB_TR + NB_TQK) {
    // TQK[j,i] = sum_k Wq[k,j] * Wk[k,i]
    int j = blk - (NB_S + NB_CONV + 2 * NB_TR);
    smem[tid] = Wq[(size_t)tid * D_ + j];
    __syncthreads();
    float acc = 0.f;
#pragma unroll 8
    for (int k = 0; k < D_; ++k) acc += smem[k] * Wk[(size_t)k * D_ + tid];
    TQK[(size_t)j * D_ + tid] = acc;
  } else if (blk < NB_S + NB_CONV + 2 * NB_TR + NB_TQK + NB_WVT) {
    // WvT[j,r] = Wv[r,j]
    int t = blk - (NB_S + NB_CONV + 2 * NB_TR + NB_TQK);
    int tr = t & 7, tc = t >> 3;
    int tx = tid & 31, ty = tid >> 5;
#pragma unroll
    for (int k = 0; k < 4; ++k)
      smem[(ty + 8 * k) * 33 + tx] =
          Wv[(size_t)(tr * 32 + ty + 8 * k) * D_ + tc * 32 + tx];
    __syncthreads();
#pragma unroll
    for (int k = 0; k < 4; ++k)
      WvT[(size_t)(tc * 32 + ty + 8 * k) * D_ + tr * 32 + tx] =
          smem[tx * 33 + ty + 8 * k];
  } else {
    // ---- bucketize: counting-sort (value,type) pairs by (range,type) -------
    int bn = blk - (NB_S + NB_CONV + 2 * NB_TR + NB_TQK + NB_WVT);
    int* sval = (int*)praw;     // 1024 ints (4 KB)
    int* stype = sval + 1024;   //  256 ints (1 KB)
    int* sbin = stype + 256;    //  256 ints (1 KB): histogram -> prefix -> ctr
    int* srng = sbin + 256;     //    4 ints: range starts
    const int* vp = kb_values + (size_t)bn * LN * LV;
    for (int i = tid; i < LN * LV; i += 256) sval[i] = vp[i];
    stype[tid] = kb_types[(size_t)bn * LN + tid];
    sbin[tid] = 0;
    __syncthreads();
    int ty = stype[tid];
    int vv[4];
#pragma unroll
    for (int j = 0; j < 4; ++j) {
      vv[j] = sval[tid * 4 + j];
      atomicAdd(&sbin[((vv[j] >> 13) << 6) | ty], 1);
    }
    __syncthreads();
    if (tid < 64) {  // wave 0: exclusive prefix over 256 bins
      int run = 0;
#pragma unroll
      for (int c = 0; c < 4; ++c) {
        int x = sbin[c * 64 + tid];
        int orig = x;
        for (int o = 1; o < 64; o <<= 1) {
          int y = __shfl_up(x, o);
          if ((int)tid >= o) x += y;
        }
        sbin[c * 64 + tid] = x - orig + run;  // exclusive global prefix
        run += __shfl(x, 63);                 // chunk total
      }
    }
    __syncthreads();
    if (tid < 4) {
      srng[tid] = sbin[tid << 6];
      int e = (tid == 3) ? (LN * LV) : sbin[(tid + 1) << 6];
      counts[bn * 4 + tid] = min(e - sbin[tid << 6], ECAP);
    }
    __syncthreads();
#pragma unroll
    for (int j = 0; j < 4; ++j) {
      int v = vv[j];
      int r = v >> 13;
      int pos = atomicAdd(&sbin[(r << 6) | ty], 1) - srng[r];
      if (pos < ECAP)
        entries[(size_t)(bn * 4 + r) * ECAP + pos] = v | (ty << 16);
    }
  }
}

// ---------------- K_rootsg: range-partitioned gather + gates + tvec ---------
// Gather: blk%8 = 2r/2r+1 -> range r pinned to XCD pair (round-robin dispatch)
// so each XCD's 4 MB L2 holds its 4 MB C0h slice. Inner loop is BRANCH-FREE
// and 4-entry batched: 8 independent loads in flight per iteration (4 C0h
// rows, 4 T_emb rows), x2 via unroll. T_emb loaded unconditionally per entry
// (64 KB, L1-hot since entries are type-sorted) -- the old run-boundary branch
// blocked all compiler pipelining (1 load in flight -> 178 cyc/entry).
// LDS union shrunk to 6 KB (gates now chunk xs by 64 columns).
#define NBG 4096
__global__ __launch_bounds__(256) void k_rootsg(
    const int* __restrict__ counts, const int* __restrict__ entries,
    const ushort_t* __restrict__ C0h, const float* __restrict__ T_emb,
    const int* __restrict__ dec, const float* __restrict__ C0,
    const float* __restrict__ hidden, const float* __restrict__ W_ihT,
    const float* __restrict__ W_hhT, const float* __restrict__ TQK,
    const float* __restrict__ b_ih, const float* __restrict__ b_hh,
    float* __restrict__ part, float* __restrict__ gi, float* __restrict__ gh,
    float* __restrict__ tvec) {
  __shared__ __align__(16) char smem_raw[6144];
  int blk = blockIdx.x, tid = threadIdx.x;
  if (blk < NBG) {
    int slot = blk & 7;
    int r = slot >> 1;
    int bn = ((blk >> 3) << 1) | (slot & 1);
    int bucket = bn * 4 + r;
    int cnt = counts[bucket];
    const int* ge = entries + (size_t)bucket * ECAP;
    int* ent = (int*)smem_raw;                // ECAP ints (1408 B)
    float* psum = (float*)(smem_raw + 1536);  // 4*256 floats (4 KB)
    for (int i = tid; i < cnt; i += 256) ent[i] = ge[i];
    __syncthreads();
    int lane = tid & 63, team = tid >> 6;
    int chunk = ((cnt + 15) >> 4) << 2;  // multiple of 4; 4*chunk >= cnt
    int k0 = team * chunk;
    int k1 = min(cnt, k0 + chunk);
    float a0 = 0.f, a1 = 0.f, a2 = 0.f, a3 = 0.f;
    int k = k0;
#pragma unroll 2
    for (; k + 4 <= k1; k += 4) {
      int4 e4 = *(const int4*)(ent + k);  // ds_read_b128 (k0 mult of 4)
      const uint2* r0 = (const uint2*)(C0h + ((size_t)(e4.x & 0xFFFF) << 8));
      const uint2* r1 = (const uint2*)(C0h + ((size_t)(e4.y & 0xFFFF) << 8));
      const uint2* r2 = (const uint2*)(C0h + ((size_t)(e4.z & 0xFFFF) << 8));
      const uint2* r3 = (const uint2*)(C0h + ((size_t)(e4.w & 0xFFFF) << 8));
      uint2 u0 = r0[lane];
      uint2 u1 = r1[lane];
      uint2 u2 = r2[lane];
      uint2 u3 = r3[lane];
      float4 t0 = ((const float4*)(T_emb + ((size_t)(e4.x >> 16) << 8)))[lane];
      float4 t1 = ((const float4*)(T_emb + ((size_t)(e4.y >> 16) << 8)))[lane];
      float4 t2 = ((const float4*)(T_emb + ((size_t)(e4.z >> 16) << 8)))[lane];
      float4 t3 = ((const float4*)(T_emb + ((size_t)(e4.w >> 16) << 8)))[lane];
      a0 += t0.x * bflo(u0.x) + t1.x * bflo(u1.x) + t2.x * bflo(u2.x) +
            t3.x * bflo(u3.x);
      a1 += t0.y * bfhi(u0.x) + t1.y * bfhi(u1.x) + t2.y * bfhi(u2.x) +
            t3.y * bfhi(u3.x);
      a2 += t0.z * bflo(u0.y) + t1.z * bflo(u1.y) + t2.z * bflo(u2.y) +
            t3.z * bflo(u3.y);
      a3 += t0.w * bfhi(u0.y) + t1.w * bfhi(u1.y) + t2.w * bfhi(u2.y) +
            t3.w * bfhi(u3.y);
    }
    for (; k < k1; ++k) {  // tail (<4 entries)
      int e = ent[k];
      uint2 u = ((const uint2*)(C0h + ((size_t)(e & 0xFFFF) << 8)))[lane];
      float4 t = ((const float4*)(T_emb + ((size_t)(e >> 16) << 8)))[lane];
      a0 += t.x * bflo(u.x);
      a1 += t.y * bfhi(u.x);
      a2 += t.z * bflo(u.y);
      a3 += t.w * bfhi(u.y);
    }
    psum[team * D_ + 4 * lane + 0] = a0;
    psum[team * D_ + 4 * lane + 1] = a1;
    psum[team * D_ + 4 * lane + 2] = a2;
    psum[team * D_ + 4 * lane + 3] = a3;
    __syncthreads();
    float rsl = psum[0 * D_ + tid] + psum[1 * D_ + tid] + psum[2 * D_ + tid] +
                psum[3 * D_ + tid];
    part[(size_t)bucket * D_ + tid] = rsl;
  } else {
    int g = blk - NBG;  // 0..2: gi, 3..5: gh, 6: tvec
    float* xs = (float*)smem_raw;  // [16][64] = 4 KB, chunked over j
    float acc[B_];
    if (g < 3) {
      int i = g * 256 + tid;
      float bias = b_ih[i];
#pragma unroll
      for (int b = 0; b < B_; ++b) acc[b] = bias;
      for (int c = 0; c < 4; ++c) {
        __syncthreads();
#pragma unroll
        for (int idx = tid; idx < B_ * 64; idx += 256) {
          int b = idx >> 6, jj = idx & 63;
          xs[idx] = C0[(size_t)dec[b] * D_ + c * 64 + jj];
        }
        __syncthreads();
#pragma unroll 4
        for (int jj = 0; jj < 64; ++jj) {
          float w = W_ihT[(size_t)(c * 64 + jj) * 768 + i];
#pragma unroll
          for (int b = 0; b < B_; ++b) acc[b] += xs[b * 64 + jj] * w;
        }
      }
#pragma unroll
      for (int b = 0; b < B_; ++b) gi[(size_t)b * 768 + i] = acc[b];
    } else if (g < 6) {
      int i = (g - 3) * 256 + tid;
      float bias = b_hh[i];
#pragma unroll
      for (int b = 0; b < B_; ++b) acc[b] = bias;
      for (int c = 0; c < 4; ++c) {
        __syncthreads();
#pragma unroll
        for (int idx = tid; idx < B_ * 64; idx += 256) {
          int b = idx >> 6, jj = idx & 63;
          xs[idx] = hidden[b * D_ + c * 64 + jj];
        }
        __syncthreads();
#pragma unroll 4
        for (int jj = 0; jj < 64; ++jj) {
          float w = W_hhT[(size_t)(c * 64 + jj) * 768 + i];
#pragma unroll
          for (int b = 0; b < B_; ++b) acc[b] += xs[b * 64 + jj] * w;
        }
      }
#pragma unroll
      for (int b = 0; b < B_; ++b) gh[(size_t)b * 768 + i] = acc[b];
    } else {
#pragma unroll
      for (int b = 0; b < B_; ++b) acc[b] = 0.f;
      for (int c = 0; c < 4; ++c) {
        __syncthreads();
#pragma unroll
        for (int idx = tid; idx < B_ * 64; idx += 256) {
          int b = idx >> 6, jj = idx & 63;
          xs[idx] = hidden[b * D_ + c * 64 + jj];
        }
        __syncthreads();
#pragma unroll 4
        for (int jj = 0; jj < 64; ++jj) {
          float w = TQK[(size_t)(c * 64 + jj) * D_ + tid];
#pragma unroll
          for (int b = 0; b < B_; ++b) acc[b] += xs[b * 64 + jj] * w;
        }
      }
#pragma unroll
      for (int b = 0; b < B_; ++b) tvec[b * D_ + tid] = acc[b];
    }
  }
}

// ---------------- K_mid: scores + rsum (1024 blocks) + S transpose (1536) ---
__global__ __launch_bounds__(256) void k_mid(
    const float* __restrict__ part, const float* __restrict__ tvec,
    const float* __restrict__ S, float* __restrict__ scores,
    float* __restrict__ ST, float* __restrict__ rsum) {
  int blk = blockIdx.x, tid = threadIdx.x;
  if (blk < 1024) {
    int b = blk >> 6;
    const float* p = part + (size_t)blk * 4 * D_;
    float rv = p[tid] + p[D_ + tid] + p[2 * D_ + tid] + p[3 * D_ + tid];
    rsum[(size_t)blk * D_ + tid] = rv;
    float sc = rv * tvec[b * D_ + tid];
    float sm = rv;
    __shared__ float red[8];
    int lane = tid & 63, wave = tid >> 6;
    for (int o = 32; o > 0; o >>= 1) {
      sc += __shfl_xor(sc, o);
      sm += __shfl_xor(sm, o);
    }
    if (lane == 0) { red[wave] = sc; red[4 + wave] = sm; }
    __syncthreads();
    if (tid == 0) {
      float SC = red[0] + red[1] + red[2] + red[3];
      float SM = red[4] + red[5] + red[6] + red[7];
      scores[blk] = (SM == 0.0f) ? SC - 1000000000.0f : SC;
    }
  } else {
    // ST[hb][d][m] = S[hb][m][d]
    int t = blk - 1024;
    int hb = t >> 5;
    int tile = t & 31;
    int tm = tile & 3, td = tile >> 2;
    int tx = tid & 31, ty = tid >> 5;
    __shared__ float sm2[32 * 33];
    const float* Sp = S + (size_t)hb * M_ * D_;
    float* STp = ST + (size_t)hb * D_ * M_;
#pragma unroll
    for (int k = 0; k < 4; ++k)
      sm2[(ty + 8 * k) * 33 + tx] =
          Sp[(size_t)(tm * 32 + ty + 8 * k) * D_ + td * 32 + tx];
    __syncthreads();
#pragma unroll
    for (int k = 0; k < 4; ++k)
      STp[(size_t)(td * 32 + ty + 8 * k) * M_ + tm * 32 + tx] =
          sm2[tx * 33 + ty + 8 * k];
  }
}

// ---------------- K_chain: softmax/rbar/feat/GRU/hops (grid=16) -------------
__global__ __launch_bounds__(256) void k_chain(
    const float* __restrict__ scores, const float* __restrict__ rsum,
    const float* __restrict__ WvT, const float* __restrict__ gi,
    const float* __restrict__ gh, const float* __restrict__ hidden,
    const float* __restrict__ S, const float* __restrict__ ST,
    float* __restrict__ h_new_out, float* __restrict__ cat,
    float* __restrict__ p_ptr) {
  int b = blockIdx.x, tid = threadIdx.x;
  __shared__ float wsh[NT], rs[D_], us[D_], lo[M_], loB[M_], pr[M_];
  if (tid < NT) {
    float s = scores[b * NT + tid];
    float m = s;
    for (int o = 32; o > 0; o >>= 1) m = fmaxf(m, __shfl_xor(m, o));
    float e = expf(s - m);
    float sum = e;
    for (int o = 32; o > 0; o >>= 1) sum += __shfl_xor(sum, o);
    wsh[tid] = e / sum;
  }
  __syncthreads();
  float rb = 0.f;
#pragma unroll 16
  for (int n = 0; n < NT; ++n)
    rb += wsh[n] * rsum[(size_t)(b * NT + n) * D_ + tid];
  rs[tid] = rb;
  __syncthreads();
  float feat = 0.f;
#pragma unroll 16
  for (int j = 0; j < D_; ++j) feat += rs[j] * WvT[(size_t)j * D_ + tid];
  {
    float i_r = gi[(size_t)b * 768 + tid];
    float i_z = gi[(size_t)b * 768 + 256 + tid];
    float i_n = gi[(size_t)b * 768 + 512 + tid];
    float h_r = gh[(size_t)b * 768 + tid];
    float h_z = gh[(size_t)b * 768 + 256 + tid];
    float h_n = gh[(size_t)b * 768 + 512 + tid];
    float h = hidden[b * D_ + tid];
    float r = 1.f / (1.f + expf(-(i_r + h_r)));
    float z = 1.f / (1.f + expf(-(i_z + h_z)));
    float nn = tanhf(i_n + r * h_n);
    float hn = (1.f - z) * nn + z * h;
    h_new_out[b * D_ + tid] = hn;
    float u0 = hn + feat;
    us[tid] = u0;
    cat[b * 512 + tid] = u0;
  }
  __syncthreads();
  for (int h = 0; h < 3; ++h) {
    {
      int m = tid & 127;
      int half = tid >> 7;
      const float* STp = ST + (((size_t)h * B_ + b) * D_ + half * 128) * M_;
      float l = 0.f;
#pragma unroll 16
      for (int d = 0; d < 128; ++d)
        l += us[half * 128 + d] * STp[(size_t)d * M_ + m];
      if (half == 0) lo[m] = l; else loB[m] = l;
    }
    __syncthreads();
    if (h == 2) {
      if (tid < M_) p_ptr[b * M_ + tid] = lo[tid] + loB[tid];
      break;
    }
    if (tid < 64) {
      float l0 = lo[tid] + loB[tid], l1 = lo[tid + 64] + loB[tid + 64];
      float a = fmaxf(l0, l1);
      for (int o = 32; o > 0; o >>= 1) a = fmaxf(a, __shfl_xor(a, o));
      float e0 = expf(l0 - a), e1 = expf(l1 - a);
      float s = e0 + e1;
      for (int o = 32; o > 0; o >>= 1) s += __shfl_xor(s, o);
      pr[tid] = e0 / s;
      pr[tid + 64] = e1 / s;
    }
    __syncthreads();
    {
      const float* Sn = S + (((size_t)(h + 1) * B_ + b) * M_) * D_;
      float o = 0.f;
#pragma unroll 16
      for (int m = 0; m < M_; ++m) o += pr[m] * Sn[(size_t)m * D_ + tid];
      if (h == 0) cat[b * 512 + D_ + tid] = o;
      us[tid] += o;
    }
    __syncthreads();
  }
}

// ---------------- K_pvocab: p_vocab = cat @ W1_w^T + b ----------------------
__global__ __launch_bounds__(256) void k_pvocab(
    const float* __restrict__ cat, const float* __restrict__ W1_w,
    const float* __restrict__ W1_b, float* __restrict__ out) {
  int blk = blockIdx.x, tid = threadIdx.x;
  int row = tid & 63, q = tid >> 6;  // q in 0..3 (k quarter)
  int v = blk * 64 + row;
  __shared__ float cs[B_ * 512];
  __shared__ float ps[3][64][B_];  // quarters 1..3 partials (12 KB)
  for (int i = tid; i < B_ * 512; i += 256) cs[i] = cat[i];
  __syncthreads();
  const float4* wrow = (const float4*)(W1_w + (size_t)v * 512 + q * 128);
  float acc[B_];
#pragma unroll
  for (int b = 0; b < B_; ++b) acc[b] = 0.f;
#pragma unroll 4
  for (int k4 = 0; k4 < 32; ++k4) {
    float4 w = wrow[k4];
#pragma unroll
    for (int b = 0; b < B_; ++b) {
      const float* c = &cs[b * 512 + q * 128 + k4 * 4];
      acc[b] += w.x * c[0] + w.y * c[1] + w.z * c[2] + w.w * c[3];
    }
  }
  if (q > 0) {
#pragma unroll
    for (int b = 0; b < B_; ++b) ps[q - 1][row][b] = acc[b];
  }
  __syncthreads();
  if (q == 0) {
    float bb = W1_b[v];
#pragma unroll
    for (int b = 0; b < B_; ++b)
      out[(size_t)b * VOCAB_ + v] =
          acc[b] + ps[0][row][b] + ps[1][row][b] + ps[2][row][b] + bb;
  }
}

extern "C" void kernel_launch(void* const* d_in, const int* in_sizes, int n_in,
                              void* d_out, int out_size, void* d_ws,
                              size_t ws_size, hipStream_t stream) {
  const int* decoder_input = (const int*)d_in[0];
  const int* story = (const int*)d_in[1];
  const float* hidden = (const float*)d_in[2];
  const int* kb_values = (const int*)d_in[3];
  const int* kb_types = (const int*)d_in[4];
  const float* C = (const float*)d_in[7];
  const float* T_emb = (const float*)d_in[8];
  const float* Wq = (const float*)d_in[9];
  const float* Wk = (const float*)d_in[10];
  const float* Wv = (const float*)d_in[11];
  const float* W1_w = (const float*)d_in[12];
  const float* W1_b = (const float*)d_in[13];
  const float* W_ih = (const float*)d_in[14];
  const float* W_hh = (const float*)d_in[15];
  const float* b_ih = (const float*)d_in[16];
  const float* b_hh = (const float*)d_in[17];

  float* out = (float*)d_out;
  float* p_ptr = out;                          // (16,128)
  float* p_vocab = out + B_ * M_;              // (16,32000)
  float* h_new = out + B_ * M_ + B_ * VOCAB_;  // (16,256)

  // workspace layout (floats). entries aliases into the wtmp tail (dead by
  // k_mid, when ST overwrites); WvT sits past both ST and entries.
  float* ws = (float*)d_ws;
  float* S = ws;                           // 1,572,864
  float* part = S + 3 * B_ * M_ * D_;      // 1,048,576 (B*NT*4ranges*D)
  float* rsum = part + B_ * NT * 4 * D_;   //   262,144
  float* cat = rsum + B_ * NT * D_;        //     8,192
  float* scores = cat + B_ * 512;          //     1,024
  float* gi = scores + B_ * NT;            //    12,288
  float* gh = gi + B_ * 768;               //    12,288
  float* tvec = gh + B_ * 768;             //     4,096
  int* counts = (int*)(tvec + B_ * D_);    //     4,096 ints
  ushort_t* C0h = (ushort_t*)(counts + 4096);  // 8,192,000 ushorts
  float* wtmp = (float*)(C0h + (size_t)VOCAB_ * D_);
  float* W_ihT = wtmp;                        //   196,608
  float* W_hhT = W_ihT + 768 * D_;            //   196,608
  float* TQK = W_hhT + 768 * D_;              //    65,536
  int* entries = (int*)(TQK + D_ * D_);       // 1,441,792 ints (4096*ECAP)
  float* ST = wtmp;                           // alias: 1,572,864 (k_mid+)
  float* WvT = wtmp + (458752 + 1441792);     //    65,536 (past ST & entries)

  hipLaunchKernelGGL(
      k_prep, dim3(NB_S + NB_CONV + 2 * NB_TR + NB_TQK + NB_WVT + NB_BKT),
      dim3(256), 0, stream, story, C, W_ih, W_hh, Wq, Wk, Wv, kb_values,
      kb_types, S, C0h, W_ihT, W_hhT, TQK, WvT, entries, counts);
  hipLaunchKernelGGL(k_rootsg, dim3(NBG + 7), dim3(256), 0, stream, counts,
                     entries, C0h, T_emb, decoder_input, C, hidden, W_ihT,
                     W_hhT, TQK, b_ih, b_hh, part, gi, gh, tvec);
  hipLaunchKernelGGL(k_mid, dim3(1024 + 1536), dim3(256), 0, stream, part,
                     tvec, S, scores, ST, rsum);
  hipLaunchKernelGGL(k_chain, dim3(B_), dim3(256), 0, stream, scores, rsum,
                     WvT, gi, gh, hidden, S, ST, h_new, cat, p_ptr);
  hipLaunchKernelGGL(k_pvocab, dim3(VOCAB_ / 64), dim3(256), 0, stream, cat,
                     W1_w, W1_b, p_vocab);
}

// Round 3
// 389.937 us; speedup vs baseline: 1.0310x; 1.0310x over previous
//
#include <hip/hip_runtime.h>
#include <hip/hip_bf16.h>
#include <math.h>

#define B_ 16
#define NT 64
#define LN 256
#define LV 4
#define D_ 256
#define VOCAB_ 32000
#define M_ 128
#define LS 4
#define ECAP 352  // per-(bn,range) entry capacity; mean 256, sigma ~14 -> 6.9 sigma

typedef unsigned short ushort_t;
typedef unsigned int uint_t;

__device__ __forceinline__ ushort_t f2bf(float f) {
  uint_t u = __float_as_uint(f);
  uint_t r = u + 0x7FFFu + ((u >> 16) & 1u);
  return (ushort_t)(r >> 16);
}
__device__ __forceinline__ float bflo(uint_t u) {
  return __uint_as_float(u << 16);
}
__device__ __forceinline__ float bfhi(uint_t u) {
  return __uint_as_float(u & 0xFFFF0000u);
}

// ---------------- K_prep: S gather | C0->bf16 | W_ih^T | W_hh^T | TQK | WvT
// | bucketize kb entries by (value-range, type) -------------------------------
#define NB_S (3 * B_ * M_)  // 6144
#define NB_CONV 2048
#define NB_TR 192   // 768x256 -> 24x8 tiles of 32x32 (per weight)
#define NB_TQK 256
#define NB_WVT 64   // 256x256 -> 8x8 tiles
#define NB_BKT (B_ * NT)  // 1024 bucketing blocks
__global__ __launch_bounds__(256) void k_prep(
    const int* __restrict__ story, const float* __restrict__ C,
    const float* __restrict__ W_ih, const float* __restrict__ W_hh,
    const float* __restrict__ Wq, const float* __restrict__ Wk,
    const float* __restrict__ Wv, const int* __restrict__ kb_values,
    const int* __restrict__ kb_types, float* __restrict__ S,
    ushort_t* __restrict__ C0h, float* __restrict__ W_ihT,
    float* __restrict__ W_hhT, float* __restrict__ TQK,
    float* __restrict__ WvT, int* __restrict__ entries,
    int* __restrict__ counts) {
  __shared__ __align__(16) char praw[6400];
  float* smem = (float*)praw;  // 32*33 floats fit (4224 B)
  int blk = blockIdx.x, tid = threadIdx.x;
  if (blk < NB_S) {
    int h = blk / (B_ * M_);
    int bm = blk % (B_ * M_);
    const int* st = story + (size_t)bm * LS;
    const float* Ch = C + (size_t)h * VOCAB_ * D_;
    float s = Ch[(size_t)st[0] * D_ + tid] + Ch[(size_t)st[1] * D_ + tid] +
              Ch[(size_t)st[2] * D_ + tid] + Ch[(size_t)st[3] * D_ + tid];
    S[(size_t)blk * D_ + tid] = s;
  } else if (blk < NB_S + NB_CONV) {
    int n4 = VOCAB_ * D_ / 4;
    for (int i = (blk - NB_S) * 256 + tid; i < n4; i += NB_CONV * 256) {
      float4 f = ((const float4*)C)[i];
      uint2 packed;
      packed.x = (uint_t)f2bf(f.x) | ((uint_t)f2bf(f.y) << 16);
      packed.y = (uint_t)f2bf(f.z) | ((uint_t)f2bf(f.w) << 16);
      ((uint2*)C0h)[i] = packed;
    }
  } else if (blk < NB_S + NB_CONV + 2 * NB_TR) {
    int t = blk - (NB_S + NB_CONV);
    const float* W = W_ih;
    float* WT = W_ihT;
    if (t >= NB_TR) { t -= NB_TR; W = W_hh; WT = W_hhT; }
    const int R = 768;
    int tr = t % (R / 32), tc = t / (R / 32);
    int tx = tid & 31, ty = tid >> 5;
#pragma unroll
    for (int k = 0; k < 4; ++k)
      smem[(ty + 8 * k) * 33 + tx] =
          W[(size_t)(tr * 32 + ty + 8 * k) * D_ + tc * 32 + tx];
    __syncthreads();
#pragma unroll
    for (int k = 0; k < 4; ++k)
      WT[(size_t)(tc * 32 + ty + 8 * k) * R + tr * 32 + tx] =
          smem[tx * 33 + ty + 8 * k];
  } else if (blk < NB_S + NB_CONV + 2 * NB_TR + NB_TQK) {
    // TQK[j,i] = sum_k Wq[k,j] * Wk[k,i]
    int j = blk - (NB_S + NB_CONV + 2 * NB_TR);
    smem[tid] = Wq[(size_t)tid * D_ + j];
    __syncthreads();
    float acc = 0.f;
#pragma unroll 8
    for (int k = 0; k < D_; ++k) acc += smem[k] * Wk[(size_t)k * D_ + tid];
    TQK[(size_t)j * D_ + tid] = acc;
  } else if (blk < NB_S + NB_CONV + 2 * NB_TR + NB_TQK + NB_WVT) {
    // WvT[j,r] = Wv[r,j]
    int t = blk - (NB_S + NB_CONV + 2 * NB_TR + NB_TQK);
    int tr = t & 7, tc = t >> 3;
    int tx = tid & 31, ty = tid >> 5;
#pragma unroll
    for (int k = 0; k < 4; ++k)
      smem[(ty + 8 * k) * 33 + tx] =
          Wv[(size_t)(tr * 32 + ty + 8 * k) * D_ + tc * 32 + tx];
    __syncthreads();
#pragma unroll
    for (int k = 0; k < 4; ++k)
      WvT[(size_t)(tc * 32 + ty + 8 * k) * D_ + tr * 32 + tx] =
          smem[tx * 33 + ty + 8 * k];
  } else {
    // ---- bucketize: counting-sort (value,type) pairs by (range,type) -------
    int bn = blk - (NB_S + NB_CONV + 2 * NB_TR + NB_TQK + NB_WVT);
    int* sval = (int*)praw;     // 1024 ints (4 KB)
    int* stype = sval + 1024;   //  256 ints (1 KB)
    int* sbin = stype + 256;    //  256 ints (1 KB): histogram -> prefix -> ctr
    int* srng = sbin + 256;     //    4 ints: range starts
    const int* vp = kb_values + (size_t)bn * LN * LV;
    for (int i = tid; i < LN * LV; i += 256) sval[i] = vp[i];
    stype[tid] = kb_types[(size_t)bn * LN + tid];
    sbin[tid] = 0;
    __syncthreads();
    int ty = stype[tid];
    int vv[4];
#pragma unroll
    for (int j = 0; j < 4; ++j) {
      vv[j] = sval[tid * 4 + j];
      atomicAdd(&sbin[((vv[j] >> 13) << 6) | ty], 1);
    }
    __syncthreads();
    if (tid < 64) {  // wave 0: exclusive prefix over 256 bins
      int run = 0;
#pragma unroll
      for (int c = 0; c < 4; ++c) {
        int x = sbin[c * 64 + tid];
        int orig = x;
        for (int o = 1; o < 64; o <<= 1) {
          int y = __shfl_up(x, o);
          if ((int)tid >= o) x += y;
        }
        sbin[c * 64 + tid] = x - orig + run;  // exclusive global prefix
        run += __shfl(x, 63);                 // chunk total
      }
    }
    __syncthreads();
    if (tid < 4) {
      srng[tid] = sbin[tid << 6];
      int e = (tid == 3) ? (LN * LV) : sbin[(tid + 1) << 6];
      counts[bn * 4 + tid] = min(e - sbin[tid << 6], ECAP);
    }
    __syncthreads();
#pragma unroll
    for (int j = 0; j < 4; ++j) {
      int v = vv[j];
      int r = v >> 13;
      int pos = atomicAdd(&sbin[(r << 6) | ty], 1) - srng[r];
      if (pos < ECAP)
        entries[(size_t)(bn * 4 + r) * ECAP + pos] = v | (ty << 16);
    }
  }
}

// ---------------- K_rootsg: range-partitioned gather + gates + tvec ---------
// 512 gather blocks x 512 threads: blk%8 -> XCD (round-robin dispatch); range
// r = (blk&7)>>1 pinned to XCD pair so each XCD's 4 MB L2 holds its C0h slice.
// Exactly 2 blocks/CU (grid AND 63KB-LDS both give 2) -> 16 waves/CU, one
// round, no re-staging. Per block: T_emb rows 1..63 staged in LDS (kills the
// 1 GB T_emb L2 traffic that sank round 2); each WAVE owns one whole bucket
// (~256 entries), so no cross-team reduction. Entry words are wave-uniform ->
// readfirstlane makes C0h row bases SGPRs (no per-load 64-bit VALU math).
#define NBG 512
__global__ __launch_bounds__(512) void k_rootsg(
    const int* __restrict__ counts, const int* __restrict__ entries,
    const ushort_t* __restrict__ C0h, const float* __restrict__ T_emb,
    const int* __restrict__ dec, const float* __restrict__ C0,
    const float* __restrict__ hidden, const float* __restrict__ W_ihT,
    const float* __restrict__ W_hhT, const float* __restrict__ TQK,
    const float* __restrict__ b_ih, const float* __restrict__ b_hh,
    float* __restrict__ part, float* __restrict__ gi, float* __restrict__ gh,
    float* __restrict__ tvec) {
  __shared__ __align__(16) char smem_raw[64512];  // 63 KB: T_emb rows 1..63
  int blk = blockIdx.x, tid = threadIdx.x;
  if (blk < NBG) {
    // stage T_emb rows 1..63 (types are 1..63; row 0 never referenced)
    const float4* Tg = (const float4*)(T_emb + D_);
    float4* t4s = (float4*)smem_raw;
    for (int i = tid; i < 63 * 64; i += 512) t4s[i] = Tg[i];
    __syncthreads();
    int wid = tid >> 6, lane = tid & 63;
    int slot = blk & 7;
    int r = slot >> 1, sub = slot & 1;
    int bn = (((blk >> 3) << 1) | sub) * 8 + wid;
    int bucket = bn * 4 + r;
    int cnt = counts[bucket];
    const int* ge = entries + (size_t)bucket * ECAP;
    const int4* ge4 = (const int4*)ge;
    float a0 = 0.f, a1 = 0.f, a2 = 0.f, a3 = 0.f;
    int k = 0;
#pragma unroll 2
    for (; k + 4 <= cnt; k += 4) {
      int4 e4 = ge4[k >> 2];  // wave-uniform 16B read
      int ex = __builtin_amdgcn_readfirstlane(e4.x);
      int ey = __builtin_amdgcn_readfirstlane(e4.y);
      int ez = __builtin_amdgcn_readfirstlane(e4.z);
      int ew = __builtin_amdgcn_readfirstlane(e4.w);
      uint2 u0 = ((const uint2*)(C0h + ((size_t)(ex & 0xFFFF) << 8)))[lane];
      uint2 u1 = ((const uint2*)(C0h + ((size_t)(ey & 0xFFFF) << 8)))[lane];
      uint2 u2 = ((const uint2*)(C0h + ((size_t)(ez & 0xFFFF) << 8)))[lane];
      uint2 u3 = ((const uint2*)(C0h + ((size_t)(ew & 0xFFFF) << 8)))[lane];
      float4 t0 = t4s[((ex >> 16) - 1) * 64 + lane];
      float4 t1 = t4s[((ey >> 16) - 1) * 64 + lane];
      float4 t2 = t4s[((ez >> 16) - 1) * 64 + lane];
      float4 t3 = t4s[((ew >> 16) - 1) * 64 + lane];
      a0 += t0.x * bflo(u0.x) + t1.x * bflo(u1.x) + t2.x * bflo(u2.x) +
            t3.x * bflo(u3.x);
      a1 += t0.y * bfhi(u0.x) + t1.y * bfhi(u1.x) + t2.y * bfhi(u2.x) +
            t3.y * bfhi(u3.x);
      a2 += t0.z * bflo(u0.y) + t1.z * bflo(u1.y) + t2.z * bflo(u2.y) +
            t3.z * bflo(u3.y);
      a3 += t0.w * bfhi(u0.y) + t1.w * bfhi(u1.y) + t2.w * bfhi(u2.y) +
            t3.w * bfhi(u3.y);
    }
    for (; k < cnt; ++k) {  // tail (<4 entries)
      int e = __builtin_amdgcn_readfirstlane(ge[k]);
      uint2 u = ((const uint2*)(C0h + ((size_t)(e & 0xFFFF) << 8)))[lane];
      float4 t = t4s[((e >> 16) - 1) * 64 + lane];
      a0 += t.x * bflo(u.x);
      a1 += t.y * bfhi(u.x);
      a2 += t.z * bflo(u.y);
      a3 += t.w * bfhi(u.y);
    }
    float4 res;
    res.x = a0; res.y = a1; res.z = a2; res.w = a3;
    ((float4*)(part + (size_t)bucket * D_))[lane] = res;
  } else {
    int g = blk - NBG;  // 0..2: gi, 3..5: gh, 6: tvec
    float* xs = (float*)smem_raw;  // [16][64] = 4 KB, chunked over j
    float acc[B_];
    int i = (g < 3 ? g : g - 3) * 256 + tid;  // valid for tid<256
    if (g < 3) {
      float bias = (tid < 256) ? b_ih[i] : 0.f;
#pragma unroll
      for (int b = 0; b < B_; ++b) acc[b] = bias;
      for (int c = 0; c < 4; ++c) {
        __syncthreads();
        for (int idx = tid; idx < B_ * 64; idx += 512) {
          int b = idx >> 6, jj = idx & 63;
          xs[idx] = C0[(size_t)dec[b] * D_ + c * 64 + jj];
        }
        __syncthreads();
        if (tid < 256) {
#pragma unroll 4
          for (int jj = 0; jj < 64; ++jj) {
            float w = W_ihT[(size_t)(c * 64 + jj) * 768 + i];
#pragma unroll
            for (int b = 0; b < B_; ++b) acc[b] += xs[b * 64 + jj] * w;
          }
        }
      }
      if (tid < 256) {
#pragma unroll
        for (int b = 0; b < B_; ++b) gi[(size_t)b * 768 + i] = acc[b];
      }
    } else if (g < 6) {
      float bias = (tid < 256) ? b_hh[i] : 0.f;
#pragma unroll
      for (int b = 0; b < B_; ++b) acc[b] = bias;
      for (int c = 0; c < 4; ++c) {
        __syncthreads();
        for (int idx = tid; idx < B_ * 64; idx += 512) {
          int b = idx >> 6, jj = idx & 63;
          xs[idx] = hidden[b * D_ + c * 64 + jj];
        }
        __syncthreads();
        if (tid < 256) {
#pragma unroll 4
          for (int jj = 0; jj < 64; ++jj) {
            float w = W_hhT[(size_t)(c * 64 + jj) * 768 + i];
#pragma unroll
            for (int b = 0; b < B_; ++b) acc[b] += xs[b * 64 + jj] * w;
          }
        }
      }
      if (tid < 256) {
#pragma unroll
        for (int b = 0; b < B_; ++b) gh[(size_t)b * 768 + i] = acc[b];
      }
    } else {
#pragma unroll
      for (int b = 0; b < B_; ++b) acc[b] = 0.f;
      for (int c = 0; c < 4; ++c) {
        __syncthreads();
        for (int idx = tid; idx < B_ * 64; idx += 512) {
          int b = idx >> 6, jj = idx & 63;
          xs[idx] = hidden[b * D_ + c * 64 + jj];
        }
        __syncthreads();
        if (tid < 256) {
#pragma unroll 4
          for (int jj = 0; jj < 64; ++jj) {
            float w = TQK[(size_t)(c * 64 + jj) * D_ + tid];
#pragma unroll
            for (int b = 0; b < B_; ++b) acc[b] += xs[b * 64 + jj] * w;
          }
        }
      }
      if (tid < 256) {
#pragma unroll
        for (int b = 0; b < B_; ++b) tvec[b * D_ + tid] = acc[b];
      }
    }
  }
}

// ---------------- K_mid: scores + rsum (1024 blocks) + S transpose (1536) ---
__global__ __launch_bounds__(256) void k_mid(
    const float* __restrict__ part, const float* __restrict__ tvec,
    const float* __restrict__ S, float* __restrict__ scores,
    float* __restrict__ ST, float* __restrict__ rsum) {
  int blk = blockIdx.x, tid = threadIdx.x;
  if (blk < 1024) {
    int b = blk >> 6;
    const float* p = part + (size_t)blk * 4 * D_;
    float rv = p[tid] + p[D_ + tid] + p[2 * D_ + tid] + p[3 * D_ + tid];
    rsum[(size_t)blk * D_ + tid] = rv;
    float sc = rv * tvec[b * D_ + tid];
    float sm = rv;
    __shared__ float red[8];
    int lane = tid & 63, wave = tid >> 6;
    for (int o = 32; o > 0; o >>= 1) {
      sc += __shfl_xor(sc, o);
      sm += __shfl_xor(sm, o);
    }
    if (lane == 0) { red[wave] = sc; red[4 + wave] = sm; }
    __syncthreads();
    if (tid == 0) {
      float SC = red[0] + red[1] + red[2] + red[3];
      float SM = red[4] + red[5] + red[6] + red[7];
      scores[blk] = (SM == 0.0f) ? SC - 1000000000.0f : SC;
    }
  } else {
    // ST[hb][d][m] = S[hb][m][d]
    int t = blk - 1024;
    int hb = t >> 5;
    int tile = t & 31;
    int tm = tile & 3, td = tile >> 2;
    int tx = tid & 31, ty = tid >> 5;
    __shared__ float sm2[32 * 33];
    const float* Sp = S + (size_t)hb * M_ * D_;
    float* STp = ST + (size_t)hb * D_ * M_;
#pragma unroll
    for (int k = 0; k < 4; ++k)
      sm2[(ty + 8 * k) * 33 + tx] =
          Sp[(size_t)(tm * 32 + ty + 8 * k) * D_ + td * 32 + tx];
    __syncthreads();
#pragma unroll
    for (int k = 0; k < 4; ++k)
      STp[(size_t)(td * 32 + ty + 8 * k) * M_ + tm * 32 + tx] =
          sm2[tx * 33 + ty + 8 * k];
  }
}

// ---------------- K_chain: softmax/rbar/feat/GRU/hops (grid=16) -------------
__global__ __launch_bounds__(256) void k_chain(
    const float* __restrict__ scores, const float* __restrict__ rsum,
    const float* __restrict__ WvT, const float* __restrict__ gi,
    const float* __restrict__ gh, const float* __restrict__ hidden,
    const float* __restrict__ S, const float* __restrict__ ST,
    float* __restrict__ h_new_out, float* __restrict__ cat,
    float* __restrict__ p_ptr) {
  int b = blockIdx.x, tid = threadIdx.x;
  __shared__ float wsh[NT], rs[D_], us[D_], lo[M_], loB[M_], pr[M_];
  if (tid < NT) {
    float s = scores[b * NT + tid];
    float m = s;
    for (int o = 32; o > 0; o >>= 1) m = fmaxf(m, __shfl_xor(m, o));
    float e = expf(s - m);
    float sum = e;
    for (int o = 32; o > 0; o >>= 1) sum += __shfl_xor(sum, o);
    wsh[tid] = e / sum;
  }
  __syncthreads();
  float rb = 0.f;
#pragma unroll 16
  for (int n = 0; n < NT; ++n)
    rb += wsh[n] * rsum[(size_t)(b * NT + n) * D_ + tid];
  rs[tid] = rb;
  __syncthreads();
  float feat = 0.f;
#pragma unroll 16
  for (int j = 0; j < D_; ++j) feat += rs[j] * WvT[(size_t)j * D_ + tid];
  {
    float i_r = gi[(size_t)b * 768 + tid];
    float i_z = gi[(size_t)b * 768 + 256 + tid];
    float i_n = gi[(size_t)b * 768 + 512 + tid];
    float h_r = gh[(size_t)b * 768 + tid];
    float h_z = gh[(size_t)b * 768 + 256 + tid];
    float h_n = gh[(size_t)b * 768 + 512 + tid];
    float h = hidden[b * D_ + tid];
    float r = 1.f / (1.f + expf(-(i_r + h_r)));
    float z = 1.f / (1.f + expf(-(i_z + h_z)));
    float nn = tanhf(i_n + r * h_n);
    float hn = (1.f - z) * nn + z * h;
    h_new_out[b * D_ + tid] = hn;
    float u0 = hn + feat;
    us[tid] = u0;
    cat[b * 512 + tid] = u0;
  }
  __syncthreads();
  for (int h = 0; h < 3; ++h) {
    {
      int m = tid & 127;
      int half = tid >> 7;
      const float* STp = ST + (((size_t)h * B_ + b) * D_ + half * 128) * M_;
      float l = 0.f;
#pragma unroll 16
      for (int d = 0; d < 128; ++d)
        l += us[half * 128 + d] * STp[(size_t)d * M_ + m];
      if (half == 0) lo[m] = l; else loB[m] = l;
    }
    __syncthreads();
    if (h == 2) {
      if (tid < M_) p_ptr[b * M_ + tid] = lo[tid] + loB[tid];
      break;
    }
    if (tid < 64) {
      float l0 = lo[tid] + loB[tid], l1 = lo[tid + 64] + loB[tid + 64];
      float a = fmaxf(l0, l1);
      for (int o = 32; o > 0; o >>= 1) a = fmaxf(a, __shfl_xor(a, o));
      float e0 = expf(l0 - a), e1 = expf(l1 - a);
      float s = e0 + e1;
      for (int o = 32; o > 0; o >>= 1) s += __shfl_xor(s, o);
      pr[tid] = e0 / s;
      pr[tid + 64] = e1 / s;
    }
    __syncthreads();
    {
      const float* Sn = S + (((size_t)(h + 1) * B_ + b) * M_) * D_;
      float o = 0.f;
#pragma unroll 16
      for (int m = 0; m < M_; ++m) o += pr[m] * Sn[(size_t)m * D_ + tid];
      if (h == 0) cat[b * 512 + D_ + tid] = o;
      us[tid] += o;
    }
    __syncthreads();
  }
}

// ---------------- K_pvocab: p_vocab = cat @ W1_w^T + b ----------------------
__global__ __launch_bounds__(256) void k_pvocab(
    const float* __restrict__ cat, const float* __restrict__ W1_w,
    const float* __restrict__ W1_b, float* __restrict__ out) {
  int blk = blockIdx.x, tid = threadIdx.x;
  int row = tid & 63, q = tid >> 6;  // q in 0..3 (k quarter)
  int v = blk * 64 + row;
  __shared__ float cs[B_ * 512];
  __shared__ float ps[3][64][B_];  // quarters 1..3 partials (12 KB)
  for (int i = tid; i < B_ * 512; i += 256) cs[i] = cat[i];
  __syncthreads();
  const float4* wrow = (const float4*)(W1_w + (size_t)v * 512 + q * 128);
  float acc[B_];
#pragma unroll
  for (int b = 0; b < B_; ++b) acc[b] = 0.f;
#pragma unroll 4
  for (int k4 = 0; k4 < 32; ++k4) {
    float4 w = wrow[k4];
#pragma unroll
    for (int b = 0; b < B_; ++b) {
      const float* c = &cs[b * 512 + q * 128 + k4 * 4];
      acc[b] += w.x * c[0] + w.y * c[1] + w.z * c[2] + w.w * c[3];
    }
  }
  if (q > 0) {
#pragma unroll
    for (int b = 0; b < B_; ++b) ps[q - 1][row][b] = acc[b];
  }
  __syncthreads();
  if (q == 0) {
    float bb = W1_b[v];
#pragma unroll
    for (int b = 0; b < B_; ++b)
      out[(size_t)b * VOCAB_ + v] =
          acc[b] + ps[0][row][b] + ps[1][row][b] + ps[2][row][b] + bb;
  }
}

extern "C" void kernel_launch(void* const* d_in, const int* in_sizes, int n_in,
                              void* d_out, int out_size, void* d_ws,
                              size_t ws_size, hipStream_t stream) {
  const int* decoder_input = (const int*)d_in[0];
  const int* story = (const int*)d_in[1];
  const float* hidden = (const float*)d_in[2];
  const int* kb_values = (const int*)d_in[3];
  const int* kb_types = (const int*)d_in[4];
  const float* C = (const float*)d_in[7];
  const float* T_emb = (const float*)d_in[8];
  const float* Wq = (const float*)d_in[9];
  const float* Wk = (const float*)d_in[10];
  const float* Wv = (const float*)d_in[11];
  const float* W1_w = (const float*)d_in[12];
  const float* W1_b = (const float*)d_in[13];
  const float* W_ih = (const float*)d_in[14];
  const float* W_hh = (const float*)d_in[15];
  const float* b_ih = (const float*)d_in[16];
  const float* b_hh = (const float*)d_in[17];

  float* out = (float*)d_out;
  float* p_ptr = out;                          // (16,128)
  float* p_vocab = out + B_ * M_;              // (16,32000)
  float* h_new = out + B_ * M_ + B_ * VOCAB_;  // (16,256)

  // workspace layout (floats). entries aliases into the wtmp tail (dead by
  // k_mid, when ST overwrites); WvT sits past both ST and entries.
  float* ws = (float*)d_ws;
  float* S = ws;                           // 1,572,864
  float* part = S + 3 * B_ * M_ * D_;      // 1,048,576 (B*NT*4ranges*D)
  float* rsum = part + B_ * NT * 4 * D_;   //   262,144
  float* cat = rsum + B_ * NT * D_;        //     8,192
  float* scores = cat + B_ * 512;          //     1,024
  float* gi = scores + B_ * NT;            //    12,288
  float* gh = gi + B_ * 768;               //    12,288
  float* tvec = gh + B_ * 768;             //     4,096
  int* counts = (int*)(tvec + B_ * D_);    //     4,096 ints
  ushort_t* C0h = (ushort_t*)(counts + 4096);  // 8,192,000 ushorts
  float* wtmp = (float*)(C0h + (size_t)VOCAB_ * D_);
  float* W_ihT = wtmp;                        //   196,608
  float* W_hhT = W_ihT + 768 * D_;            //   196,608
  float* TQK = W_hhT + 768 * D_;              //    65,536
  int* entries = (int*)(TQK + D_ * D_);       // 1,441,792 ints (4096*ECAP)
  float* ST = wtmp;                           // alias: 1,572,864 (k_mid+)
  float* WvT = wtmp + (458752 + 1441792);     //    65,536 (past ST & entries)

  hipLaunchKernelGGL(
      k_prep, dim3(NB_S + NB_CONV + 2 * NB_TR + NB_TQK + NB_WVT + NB_BKT),
      dim3(256), 0, stream, story, C, W_ih, W_hh, Wq, Wk, Wv, kb_values,
      kb_types, S, C0h, W_ihT, W_hhT, TQK, WvT, entries, counts);
  hipLaunchKernelGGL(k_rootsg, dim3(NBG + 7), dim3(512), 0, stream, counts,
                     entries, C0h, T_emb, decoder_input, C, hidden, W_ihT,
                     W_hhT, TQK, b_ih, b_hh, part, gi, gh, tvec);
  hipLaunchKernelGGL(k_mid, dim3(1024 + 1536), dim3(256), 0, stream, part,
                     tvec, S, scores, ST, rsum);
  hipLaunchKernelGGL(k_chain, dim3(B_), dim3(256), 0, stream, scores, rsum,
                     WvT, gi, gh, hidden, S, ST, h_new, cat, p_ptr);
  hipLaunchKernelGGL(k_pvocab, dim3(VOCAB_ / 64), dim3(256), 0, stream, cat,
                     W1_w, W1_b, p_vocab);
}

// Round 4
// 381.244 us; speedup vs baseline: 1.0546x; 1.0228x over previous
//
#include <hip/hip_runtime.h>
#include <hip/hip_bf16.h>
#include <math.h>

#define B_ 16
#define NT 64
#define LN 256
#define LV 4
#define D_ 256
#define VOCAB_ 32000
#define M_ 128
#define LS 4
#define ECAP 352  // per-(bn,range) entry capacity; mean 256, sigma ~14 -> 6.9 sigma

typedef unsigned short ushort_t;
typedef unsigned int uint_t;

__device__ __forceinline__ ushort_t f2bf(float f) {
  uint_t u = __float_as_uint(f);
  uint_t r = u + 0x7FFFu + ((u >> 16) & 1u);
  return (ushort_t)(r >> 16);
}
__device__ __forceinline__ float bflo(uint_t u) {
  return __uint_as_float(u << 16);
}
__device__ __forceinline__ float bfhi(uint_t u) {
  return __uint_as_float(u & 0xFFFF0000u);
}

// ---------------- K_prep: S gather | C0->bf16 | W_ih^T | W_hh^T | TQK | WvT
// | bucketize kb entries by (value-range, type) -------------------------------
#define NB_S (3 * B_ * M_)  // 6144
#define NB_CONV 2048
#define NB_TR 192   // 768x256 -> 24x8 tiles of 32x32 (per weight)
#define NB_TQK 256
#define NB_WVT 64   // 256x256 -> 8x8 tiles
#define NB_BKT (B_ * NT)  // 1024 bucketing blocks
__global__ __launch_bounds__(256) void k_prep(
    const int* __restrict__ story, const float* __restrict__ C,
    const float* __restrict__ W_ih, const float* __restrict__ W_hh,
    const float* __restrict__ Wq, const float* __restrict__ Wk,
    const float* __restrict__ Wv, const int* __restrict__ kb_values,
    const int* __restrict__ kb_types, float* __restrict__ S,
    ushort_t* __restrict__ C0h, float* __restrict__ W_ihT,
    float* __restrict__ W_hhT, float* __restrict__ TQK,
    float* __restrict__ WvT, int* __restrict__ entries,
    int* __restrict__ counts, int* __restrict__ qctr) {
  __shared__ __align__(16) char praw[6400];
  float* smem = (float*)praw;  // 32*33 floats fit (4224 B)
  int blk = blockIdx.x, tid = threadIdx.x;
  if (blk == 0 && tid < 8) qctr[tid] = 0;  // reset k_rootsg work queues
  if (blk < NB_S) {
    int h = blk / (B_ * M_);
    int bm = blk % (B_ * M_);
    const int* st = story + (size_t)bm * LS;
    const float* Ch = C + (size_t)h * VOCAB_ * D_;
    float s = Ch[(size_t)st[0] * D_ + tid] + Ch[(size_t)st[1] * D_ + tid] +
              Ch[(size_t)st[2] * D_ + tid] + Ch[(size_t)st[3] * D_ + tid];
    S[(size_t)blk * D_ + tid] = s;
  } else if (blk < NB_S + NB_CONV) {
    int n4 = VOCAB_ * D_ / 4;
    for (int i = (blk - NB_S) * 256 + tid; i < n4; i += NB_CONV * 256) {
      float4 f = ((const float4*)C)[i];
      uint2 packed;
      packed.x = (uint_t)f2bf(f.x) | ((uint_t)f2bf(f.y) << 16);
      packed.y = (uint_t)f2bf(f.z) | ((uint_t)f2bf(f.w) << 16);
      ((uint2*)C0h)[i] = packed;
    }
  } else if (blk < NB_S + NB_CONV + 2 * NB_TR) {
    int t = blk - (NB_S + NB_CONV);
    const float* W = W_ih;
    float* WT = W_ihT;
    if (t >= NB_TR) { t -= NB_TR; W = W_hh; WT = W_hhT; }
    const int R = 768;
    int tr = t % (R / 32), tc = t / (R / 32);
    int tx = tid & 31, ty = tid >> 5;
#pragma unroll
    for (int k = 0; k < 4; ++k)
      smem[(ty + 8 * k) * 33 + tx] =
          W[(size_t)(tr * 32 + ty + 8 * k) * D_ + tc * 32 + tx];
    __syncthreads();
#pragma unroll
    for (int k = 0; k < 4; ++k)
      WT[(size_t)(tc * 32 + ty + 8 * k) * R + tr * 32 + tx] =
          smem[tx * 33 + ty + 8 * k];
  } else if (blk < NB_S + NB_CONV + 2 * NB_TR + NB_TQK) {
    // TQK[j,i] = sum_k Wq[k,j] * Wk[k,i]
    int j = blk - (NB_S + NB_CONV + 2 * NB_TR);
    smem[tid] = Wq[(size_t)tid * D_ + j];
    __syncthreads();
    float acc = 0.f;
#pragma unroll 8
    for (int k = 0; k < D_; ++k) acc += smem[k] * Wk[(size_t)k * D_ + tid];
    TQK[(size_t)j * D_ + tid] = acc;
  } else if (blk < NB_S + NB_CONV + 2 * NB_TR + NB_TQK + NB_WVT) {
    // WvT[j,r] = Wv[r,j]
    int t = blk - (NB_S + NB_CONV + 2 * NB_TR + NB_TQK);
    int tr = t & 7, tc = t >> 3;
    int tx = tid & 31, ty = tid >> 5;
#pragma unroll
    for (int k = 0; k < 4; ++k)
      smem[(ty + 8 * k) * 33 + tx] =
          Wv[(size_t)(tr * 32 + ty + 8 * k) * D_ + tc * 32 + tx];
    __syncthreads();
#pragma unroll
    for (int k = 0; k < 4; ++k)
      WvT[(size_t)(tc * 32 + ty + 8 * k) * D_ + tr * 32 + tx] =
          smem[tx * 33 + ty + 8 * k];
  } else {
    // ---- bucketize: counting-sort (value,type) pairs by (range,type) -------
    int bn = blk - (NB_S + NB_CONV + 2 * NB_TR + NB_TQK + NB_WVT);
    int* sval = (int*)praw;     // 1024 ints (4 KB)
    int* stype = sval + 1024;   //  256 ints (1 KB)
    int* sbin = stype + 256;    //  256 ints (1 KB): histogram -> prefix -> ctr
    int* srng = sbin + 256;     //    4 ints: range starts
    const int* vp = kb_values + (size_t)bn * LN * LV;
    for (int i = tid; i < LN * LV; i += 256) sval[i] = vp[i];
    stype[tid] = kb_types[(size_t)bn * LN + tid];
    sbin[tid] = 0;
    __syncthreads();
    int ty = stype[tid];
    int vv[4];
#pragma unroll
    for (int j = 0; j < 4; ++j) {
      vv[j] = sval[tid * 4 + j];
      atomicAdd(&sbin[((vv[j] >> 13) << 6) | ty], 1);
    }
    __syncthreads();
    if (tid < 64) {  // wave 0: exclusive prefix over 256 bins
      int run = 0;
#pragma unroll
      for (int c = 0; c < 4; ++c) {
        int x = sbin[c * 64 + tid];
        int orig = x;
        for (int o = 1; o < 64; o <<= 1) {
          int y = __shfl_up(x, o);
          if ((int)tid >= o) x += y;
        }
        sbin[c * 64 + tid] = x - orig + run;  // exclusive global prefix
        run += __shfl(x, 63);                 // chunk total
      }
    }
    __syncthreads();
    if (tid < 4) {
      srng[tid] = sbin[tid << 6];
      int e = (tid == 3) ? (LN * LV) : sbin[(tid + 1) << 6];
      counts[bn * 4 + tid] = min(e - sbin[tid << 6], ECAP);
    }
    __syncthreads();
#pragma unroll
    for (int j = 0; j < 4; ++j) {
      int v = vv[j];
      int r = v >> 13;
      int pos = atomicAdd(&sbin[(r << 6) | ty], 1) - srng[r];
      if (pos < ECAP)
        entries[(size_t)(bn * 4 + r) * ECAP + pos] = v | (ty << 16);
    }
  }
}

// ---------------- K_rootsg: XCC-claimed range-partitioned gather + gates ----
// The blockIdx%8->XCD assumption failed (rounds 1-3: ~86us latency wall, L2
// thrash -> L3 hits). Now each block reads its REAL XCD id via
// s_getreg(HW_REG_XCC_ID=20, gfx950-verified) and CLAIMS a work unit for the
// range pinned to its XCD pair (range r <-> XCDs {2r,2r+1}) from per-range
// atomic queues; stealing fallback keeps correctness under any dispatch
// balance (a block exits empty only after seeing all queues full => all 512
// units claimed). Entries staged in LDS per wave (no vmcnt-serialized
// readfirstlane chain); T_emb rows 1..63 staged in LDS (63 KB). unroll 2 ->
// 8 independent C0h loads in flight/wave, 64/CU outstanding >> BW*latency.
#define NBG 512
#define UNITS_PER_RANGE 128  // 1024 bn / 8 bn-per-unit
__global__ __launch_bounds__(512) void k_rootsg(
    const int* __restrict__ counts, const int* __restrict__ entries,
    const ushort_t* __restrict__ C0h, const float* __restrict__ T_emb,
    const int* __restrict__ dec, const float* __restrict__ C0,
    const float* __restrict__ hidden, const float* __restrict__ W_ihT,
    const float* __restrict__ W_hhT, const float* __restrict__ TQK,
    const float* __restrict__ b_ih, const float* __restrict__ b_hh,
    float* __restrict__ part, float* __restrict__ gi, float* __restrict__ gh,
    float* __restrict__ tvec, int* __restrict__ qctr) {
  // 63 KB T_emb + 8 waves x 352 ints entries + claim slot = 75792 B
  __shared__ __align__(16) char smem_raw[64512 + 11264 + 16];
  int blk = blockIdx.x, tid = threadIdx.x;
  if (blk < NBG) {
    float4* t4s = (float4*)smem_raw;                 // [63*64] float4
    int* ent_all = (int*)(smem_raw + 64512);         // [8][352]
    int* sunit = (int*)(smem_raw + 64512 + 11264);   // claim broadcast
    // stage T_emb rows 1..63 (types are 1..63; row 0 never referenced)
    const float4* Tg = (const float4*)(T_emb + D_);
    for (int i = tid; i < 63 * 64; i += 512) t4s[i] = Tg[i];
    if (tid == 0) {
      int xcd = __builtin_amdgcn_s_getreg(6164) & 7;  // hwreg(XCC_ID=20,0,4)
      int r0 = xcd >> 1;
      int unit = -1;
      for (int a = 0; a < 4 && unit < 0; ++a) {
        int rr = (r0 + a) & 3;
        int u = atomicAdd(&qctr[rr], 1);
        if (u < UNITS_PER_RANGE) unit = (u << 2) | rr;
      }
      sunit[0] = unit;
    }
    __syncthreads();
    int unit = sunit[0];
    if (unit < 0) return;  // all 512 units already claimed
    int rr = unit & 3, u = unit >> 2;
    int wid = tid >> 6, lane = tid & 63;
    int bn = u * 8 + wid;
    int bucket = bn * 4 + rr;
    int cnt = counts[bucket];
    const int* ge = entries + (size_t)bucket * ECAP;
    int* ent = ent_all + wid * ECAP;
    for (int i = lane; i < cnt; i += 64) ent[i] = ge[i];  // wave-local stage
    float a0 = 0.f, a1 = 0.f, a2 = 0.f, a3 = 0.f;
    int k = 0;
#pragma unroll 2
    for (; k + 4 <= cnt; k += 4) {
      int4 e4 = *(const int4*)(ent + k);  // LDS b128, same-addr broadcast
      int ex = __builtin_amdgcn_readfirstlane(e4.x);
      int ey = __builtin_amdgcn_readfirstlane(e4.y);
      int ez = __builtin_amdgcn_readfirstlane(e4.z);
      int ew = __builtin_amdgcn_readfirstlane(e4.w);
      uint2 u0 = ((const uint2*)(C0h + ((size_t)(ex & 0xFFFF) << 8)))[lane];
      uint2 u1 = ((const uint2*)(C0h + ((size_t)(ey & 0xFFFF) << 8)))[lane];
      uint2 u2 = ((const uint2*)(C0h + ((size_t)(ez & 0xFFFF) << 8)))[lane];
      uint2 u3 = ((const uint2*)(C0h + ((size_t)(ew & 0xFFFF) << 8)))[lane];
      float4 t0 = t4s[((ex >> 16) - 1) * 64 + lane];
      float4 t1 = t4s[((ey >> 16) - 1) * 64 + lane];
      float4 t2 = t4s[((ez >> 16) - 1) * 64 + lane];
      float4 t3 = t4s[((ew >> 16) - 1) * 64 + lane];
      a0 += t0.x * bflo(u0.x) + t1.x * bflo(u1.x) + t2.x * bflo(u2.x) +
            t3.x * bflo(u3.x);
      a1 += t0.y * bfhi(u0.x) + t1.y * bfhi(u1.x) + t2.y * bfhi(u2.x) +
            t3.y * bfhi(u3.x);
      a2 += t0.z * bflo(u0.y) + t1.z * bflo(u1.y) + t2.z * bflo(u2.y) +
            t3.z * bflo(u3.y);
      a3 += t0.w * bfhi(u0.y) + t1.w * bfhi(u1.y) + t2.w * bfhi(u2.y) +
            t3.w * bfhi(u3.y);
    }
    for (; k < cnt; ++k) {  // tail (<4 entries)
      int e = ent[k];
      int es = __builtin_amdgcn_readfirstlane(e);
      uint2 uu = ((const uint2*)(C0h + ((size_t)(es & 0xFFFF) << 8)))[lane];
      float4 t = t4s[((es >> 16) - 1) * 64 + lane];
      a0 += t.x * bflo(uu.x);
      a1 += t.y * bfhi(uu.x);
      a2 += t.z * bflo(uu.y);
      a3 += t.w * bfhi(uu.y);
    }
    float4 res;
    res.x = a0; res.y = a1; res.z = a2; res.w = a3;
    ((float4*)(part + (size_t)bucket * D_))[lane] = res;
  } else {
    int g = blk - NBG;  // 0..2: gi, 3..5: gh, 6: tvec
    float* xs = (float*)smem_raw;  // [16][64] = 4 KB, chunked over j
    float acc[B_];
    int i = (g < 3 ? g : g - 3) * 256 + tid;  // valid for tid<256
    if (g < 3) {
      float bias = (tid < 256) ? b_ih[i] : 0.f;
#pragma unroll
      for (int b = 0; b < B_; ++b) acc[b] = bias;
      for (int c = 0; c < 4; ++c) {
        __syncthreads();
        for (int idx = tid; idx < B_ * 64; idx += 512) {
          int b = idx >> 6, jj = idx & 63;
          xs[idx] = C0[(size_t)dec[b] * D_ + c * 64 + jj];
        }
        __syncthreads();
        if (tid < 256) {
#pragma unroll 4
          for (int jj = 0; jj < 64; ++jj) {
            float w = W_ihT[(size_t)(c * 64 + jj) * 768 + i];
#pragma unroll
            for (int b = 0; b < B_; ++b) acc[b] += xs[b * 64 + jj] * w;
          }
        }
      }
      if (tid < 256) {
#pragma unroll
        for (int b = 0; b < B_; ++b) gi[(size_t)b * 768 + i] = acc[b];
      }
    } else if (g < 6) {
      float bias = (tid < 256) ? b_hh[i] : 0.f;
#pragma unroll
      for (int b = 0; b < B_; ++b) acc[b] = bias;
      for (int c = 0; c < 4; ++c) {
        __syncthreads();
        for (int idx = tid; idx < B_ * 64; idx += 512) {
          int b = idx >> 6, jj = idx & 63;
          xs[idx] = hidden[b * D_ + c * 64 + jj];
        }
        __syncthreads();
        if (tid < 256) {
#pragma unroll 4
          for (int jj = 0; jj < 64; ++jj) {
            float w = W_hhT[(size_t)(c * 64 + jj) * 768 + i];
#pragma unroll
            for (int b = 0; b < B_; ++b) acc[b] += xs[b * 64 + jj] * w;
          }
        }
      }
      if (tid < 256) {
#pragma unroll
        for (int b = 0; b < B_; ++b) gh[(size_t)b * 768 + i] = acc[b];
      }
    } else {
#pragma unroll
      for (int b = 0; b < B_; ++b) acc[b] = 0.f;
      for (int c = 0; c < 4; ++c) {
        __syncthreads();
        for (int idx = tid; idx < B_ * 64; idx += 512) {
          int b = idx >> 6, jj = idx & 63;
          xs[idx] = hidden[b * D_ + c * 64 + jj];
        }
        __syncthreads();
        if (tid < 256) {
#pragma unroll 4
          for (int jj = 0; jj < 64; ++jj) {
            float w = TQK[(size_t)(c * 64 + jj) * D_ + tid];
#pragma unroll
            for (int b = 0; b < B_; ++b) acc[b] += xs[b * 64 + jj] * w;
          }
        }
      }
      if (tid < 256) {
#pragma unroll
        for (int b = 0; b < B_; ++b) tvec[b * D_ + tid] = acc[b];
      }
    }
  }
}

// ---------------- K_mid: scores + rsum (1024 blocks) + S transpose (1536) ---
__global__ __launch_bounds__(256) void k_mid(
    const float* __restrict__ part, const float* __restrict__ tvec,
    const float* __restrict__ S, float* __restrict__ scores,
    float* __restrict__ ST, float* __restrict__ rsum) {
  int blk = blockIdx.x, tid = threadIdx.x;
  if (blk < 1024) {
    int b = blk >> 6;
    const float* p = part + (size_t)blk * 4 * D_;
    float rv = p[tid] + p[D_ + tid] + p[2 * D_ + tid] + p[3 * D_ + tid];
    rsum[(size_t)blk * D_ + tid] = rv;
    float sc = rv * tvec[b * D_ + tid];
    float sm = rv;
    __shared__ float red[8];
    int lane = tid & 63, wave = tid >> 6;
    for (int o = 32; o > 0; o >>= 1) {
      sc += __shfl_xor(sc, o);
      sm += __shfl_xor(sm, o);
    }
    if (lane == 0) { red[wave] = sc; red[4 + wave] = sm; }
    __syncthreads();
    if (tid == 0) {
      float SC = red[0] + red[1] + red[2] + red[3];
      float SM = red[4] + red[5] + red[6] + red[7];
      scores[blk] = (SM == 0.0f) ? SC - 1000000000.0f : SC;
    }
  } else {
    // ST[hb][d][m] = S[hb][m][d]
    int t = blk - 1024;
    int hb = t >> 5;
    int tile = t & 31;
    int tm = tile & 3, td = tile >> 2;
    int tx = tid & 31, ty = tid >> 5;
    __shared__ float sm2[32 * 33];
    const float* Sp = S + (size_t)hb * M_ * D_;
    float* STp = ST + (size_t)hb * D_ * M_;
#pragma unroll
    for (int k = 0; k < 4; ++k)
      sm2[(ty + 8 * k) * 33 + tx] =
          Sp[(size_t)(tm * 32 + ty + 8 * k) * D_ + td * 32 + tx];
    __syncthreads();
#pragma unroll
    for (int k = 0; k < 4; ++k)
      STp[(size_t)(td * 32 + ty + 8 * k) * M_ + tm * 32 + tx] =
          sm2[tx * 33 + ty + 8 * k];
  }
}

// ---------------- K_chain: softmax/rbar/feat/GRU/hops (grid=16) -------------
__global__ __launch_bounds__(256) void k_chain(
    const float* __restrict__ scores, const float* __restrict__ rsum,
    const float* __restrict__ WvT, const float* __restrict__ gi,
    const float* __restrict__ gh, const float* __restrict__ hidden,
    const float* __restrict__ S, const float* __restrict__ ST,
    float* __restrict__ h_new_out, float* __restrict__ cat,
    float* __restrict__ p_ptr) {
  int b = blockIdx.x, tid = threadIdx.x;
  __shared__ float wsh[NT], rs[D_], us[D_], lo[M_], loB[M_], pr[M_];
  if (tid < NT) {
    float s = scores[b * NT + tid];
    float m = s;
    for (int o = 32; o > 0; o >>= 1) m = fmaxf(m, __shfl_xor(m, o));
    float e = expf(s - m);
    float sum = e;
    for (int o = 32; o > 0; o >>= 1) sum += __shfl_xor(sum, o);
    wsh[tid] = e / sum;
  }
  __syncthreads();
  float rb = 0.f;
#pragma unroll 16
  for (int n = 0; n < NT; ++n)
    rb += wsh[n] * rsum[(size_t)(b * NT + n) * D_ + tid];
  rs[tid] = rb;
  __syncthreads();
  float feat = 0.f;
#pragma unroll 16
  for (int j = 0; j < D_; ++j) feat += rs[j] * WvT[(size_t)j * D_ + tid];
  {
    float i_r = gi[(size_t)b * 768 + tid];
    float i_z = gi[(size_t)b * 768 + 256 + tid];
    float i_n = gi[(size_t)b * 768 + 512 + tid];
    float h_r = gh[(size_t)b * 768 + tid];
    float h_z = gh[(size_t)b * 768 + 256 + tid];
    float h_n = gh[(size_t)b * 768 + 512 + tid];
    float h = hidden[b * D_ + tid];
    float r = 1.f / (1.f + expf(-(i_r + h_r)));
    float z = 1.f / (1.f + expf(-(i_z + h_z)));
    float nn = tanhf(i_n + r * h_n);
    float hn = (1.f - z) * nn + z * h;
    h_new_out[b * D_ + tid] = hn;
    float u0 = hn + feat;
    us[tid] = u0;
    cat[b * 512 + tid] = u0;
  }
  __syncthreads();
  for (int h = 0; h < 3; ++h) {
    {
      int m = tid & 127;
      int half = tid >> 7;
      const float* STp = ST + (((size_t)h * B_ + b) * D_ + half * 128) * M_;
      float l = 0.f;
#pragma unroll 16
      for (int d = 0; d < 128; ++d)
        l += us[half * 128 + d] * STp[(size_t)d * M_ + m];
      if (half == 0) lo[m] = l; else loB[m] = l;
    }
    __syncthreads();
    if (h == 2) {
      if (tid < M_) p_ptr[b * M_ + tid] = lo[tid] + loB[tid];
      break;
    }
    if (tid < 64) {
      float l0 = lo[tid] + loB[tid], l1 = lo[tid + 64] + loB[tid + 64];
      float a = fmaxf(l0, l1);
      for (int o = 32; o > 0; o >>= 1) a = fmaxf(a, __shfl_xor(a, o));
      float e0 = expf(l0 - a), e1 = expf(l1 - a);
      float s = e0 + e1;
      for (int o = 32; o > 0; o >>= 1) s += __shfl_xor(s, o);
      pr[tid] = e0 / s;
      pr[tid + 64] = e1 / s;
    }
    __syncthreads();
    {
      const float* Sn = S + (((size_t)(h + 1) * B_ + b) * M_) * D_;
      float o = 0.f;
#pragma unroll 16
      for (int m = 0; m < M_; ++m) o += pr[m] * Sn[(size_t)m * D_ + tid];
      if (h == 0) cat[b * 512 + D_ + tid] = o;
      us[tid] += o;
    }
    __syncthreads();
  }
}

// ---------------- K_pvocab: p_vocab = cat @ W1_w^T + b ----------------------
__global__ __launch_bounds__(256) void k_pvocab(
    const float* __restrict__ cat, const float* __restrict__ W1_w,
    const float* __restrict__ W1_b, float* __restrict__ out) {
  int blk = blockIdx.x, tid = threadIdx.x;
  int row = tid & 63, q = tid >> 6;  // q in 0..3 (k quarter)
  int v = blk * 64 + row;
  __shared__ float cs[B_ * 512];
  __shared__ float ps[3][64][B_];  // quarters 1..3 partials (12 KB)
  for (int i = tid; i < B_ * 512; i += 256) cs[i] = cat[i];
  __syncthreads();
  const float4* wrow = (const float4*)(W1_w + (size_t)v * 512 + q * 128);
  float acc[B_];
#pragma unroll
  for (int b = 0; b < B_; ++b) acc[b] = 0.f;
#pragma unroll 4
  for (int k4 = 0; k4 < 32; ++k4) {
    float4 w = wrow[k4];
#pragma unroll
    for (int b = 0; b < B_; ++b) {
      const float* c = &cs[b * 512 + q * 128 + k4 * 4];
      acc[b] += w.x * c[0] + w.y * c[1] + w.z * c[2] + w.w * c[3];
    }
  }
  if (q > 0) {
#pragma unroll
    for (int b = 0; b < B_; ++b) ps[q - 1][row][b] = acc[b];
  }
  __syncthreads();
  if (q == 0) {
    float bb = W1_b[v];
#pragma unroll
    for (int b = 0; b < B_; ++b)
      out[(size_t)b * VOCAB_ + v] =
          acc[b] + ps[0][row][b] + ps[1][row][b] + ps[2][row][b] + bb;
  }
}

extern "C" void kernel_launch(void* const* d_in, const int* in_sizes, int n_in,
                              void* d_out, int out_size, void* d_ws,
                              size_t ws_size, hipStream_t stream) {
  const int* decoder_input = (const int*)d_in[0];
  const int* story = (const int*)d_in[1];
  const float* hidden = (const float*)d_in[2];
  const int* kb_values = (const int*)d_in[3];
  const int* kb_types = (const int*)d_in[4];
  const float* C = (const float*)d_in[7];
  const float* T_emb = (const float*)d_in[8];
  const float* Wq = (const float*)d_in[9];
  const float* Wk = (const float*)d_in[10];
  const float* Wv = (const float*)d_in[11];
  const float* W1_w = (const float*)d_in[12];
  const float* W1_b = (const float*)d_in[13];
  const float* W_ih = (const float*)d_in[14];
  const float* W_hh = (const float*)d_in[15];
  const float* b_ih = (const float*)d_in[16];
  const float* b_hh = (const float*)d_in[17];

  float* out = (float*)d_out;
  float* p_ptr = out;                          // (16,128)
  float* p_vocab = out + B_ * M_;              // (16,32000)
  float* h_new = out + B_ * M_ + B_ * VOCAB_;  // (16,256)

  // workspace layout (floats). entries aliases into the wtmp tail (dead by
  // k_mid, when ST overwrites); WvT sits past both ST and entries.
  float* ws = (float*)d_ws;
  float* S = ws;                           // 1,572,864
  float* part = S + 3 * B_ * M_ * D_;      // 1,048,576 (B*NT*4ranges*D)
  float* rsum = part + B_ * NT * 4 * D_;   //   262,144
  float* cat = rsum + B_ * NT * D_;        //     8,192
  float* scores = cat + B_ * 512;          //     1,024
  float* gi = scores + B_ * NT;            //    12,288
  float* gh = gi + B_ * 768;               //    12,288
  float* tvec = gh + B_ * 768;             //     4,096
  int* counts = (int*)(tvec + B_ * D_);    //     4,096 ints
  int* qctr = counts + 4096;               //         8 ints (work queues)
  ushort_t* C0h = (ushort_t*)(qctr + 8);   // 8,192,000 ushorts
  float* wtmp = (float*)(C0h + (size_t)VOCAB_ * D_);
  float* W_ihT = wtmp;                        //   196,608
  float* W_hhT = W_ihT + 768 * D_;            //   196,608
  float* TQK = W_hhT + 768 * D_;              //    65,536
  int* entries = (int*)(TQK + D_ * D_);       // 1,441,792 ints (4096*ECAP)
  float* ST = wtmp;                           // alias: 1,572,864 (k_mid+)
  float* WvT = wtmp + (458752 + 1441792);     //    65,536 (past ST & entries)

  hipLaunchKernelGGL(
      k_prep, dim3(NB_S + NB_CONV + 2 * NB_TR + NB_TQK + NB_WVT + NB_BKT),
      dim3(256), 0, stream, story, C, W_ih, W_hh, Wq, Wk, Wv, kb_values,
      kb_types, S, C0h, W_ihT, W_hhT, TQK, WvT, entries, counts, qctr);
  hipLaunchKernelGGL(k_rootsg, dim3(NBG + 7), dim3(512), 0, stream, counts,
                     entries, C0h, T_emb, decoder_input, C, hidden, W_ihT,
                     W_hhT, TQK, b_ih, b_hh, part, gi, gh, tvec, qctr);
  hipLaunchKernelGGL(k_mid, dim3(1024 + 1536), dim3(256), 0, stream, part,
                     tvec, S, scores, ST, rsum);
  hipLaunchKernelGGL(k_chain, dim3(B_), dim3(256), 0, stream, scores, rsum,
                     WvT, gi, gh, hidden, S, ST, h_new, cat, p_ptr);
  hipLaunchKernelGGL(k_pvocab, dim3(VOCAB_ / 64), dim3(256), 0, stream, cat,
                     W1_w, W1_b, p_vocab);
}